// Round 1
// baseline (19923.395 us; speedup 1.0000x reference)
//
#include <hip/hip_runtime.h>

typedef unsigned short u16;
typedef __attribute__((ext_vector_type(8))) short bf16x8;
typedef __attribute__((ext_vector_type(4))) float f32x4;
typedef __attribute__((ext_vector_type(4))) u16 u16x4;

// B=128, T=1024, I=512, H=1024
// ws layout (bytes):
//   xw   @ 0          : [131072][3072] bf16 = 805,306,368   (xW for i|f|g gates, row m = b*1024+t)
//   xbf  @ 805306368  : [131072][512]  bf16 = 134,217,728   (x converted)
//   wt   @ 939524096  : [3072][512]    bf16 (W^T, gates ifg) (4 MB reserved)
//   wcat @ 943718400  : [5120][1024]   bf16 = 10,485,760    (K-major: U_i|U_f|U_g|P_i|P_f columns as rows)
//   cf   @ 954204160  : 2 x [128][1024] f32 (ping-pong cell state)
//   cb   @ 955252736  : 2 x [128][1024] bf16 (bf16 shadow of c)
//   sp   @ 955777024  : [128][1024] f32 (c_prev saved at output step)
//   sn   @ 956301312  : [128][1024] f32 (c_new  saved at output step)
// total ~912 MB

__device__ __forceinline__ float bf2f(u16 u) {
  return __uint_as_float(((unsigned)u) << 16);
}
__device__ __forceinline__ u16 f2bf(float f) {
  unsigned u = __float_as_uint(f);
  u = (u + 0x7FFFu + ((u >> 16) & 1u)) >> 16;  // RNE
  return (u16)u;
}
__device__ __forceinline__ float sigm_(float x) { return 1.0f / (1.0f + __expf(-x)); }
__device__ __forceinline__ float tanh_(float x) {
  float e = __expf(2.0f * fabsf(x));
  float r = 1.0f - 2.0f / (e + 1.0f);
  return copysignf(r, x);
}
__device__ __forceinline__ void g2l16(const void* g, void* l) {
  __builtin_amdgcn_global_load_lds(
      (const __attribute__((address_space(1))) void*)g,
      (__attribute__((address_space(3))) void*)l, 16, 0, 0);
}

// ---------------- f32 -> bf16 elementwise convert ----------------
__global__ __launch_bounds__(256) void k_cvt(const float* __restrict__ in,
                                             u16* __restrict__ out, int n) {
  int i = (blockIdx.x * 256 + threadIdx.x) * 4;
  if (i >= n) return;
  const float4 v = *(const float4*)(in + i);
  u16x4 o;
  o.x = f2bf(v.x); o.y = f2bf(v.y); o.z = f2bf(v.z); o.w = f2bf(v.w);
  *(u16x4*)(out + i) = o;
}

// ------------- transpose + convert: out[j][k] = (bf16)src[k][j0+j] -------------
__global__ __launch_bounds__(256) void k_tr(const float* __restrict__ src, int ld,
                                            u16* __restrict__ out, int K) {
  __shared__ float tle[64][65];
  int j0 = blockIdx.x * 64, k0 = blockIdx.y * 64;
  int jc = threadIdx.x & 63, kq = threadIdx.x >> 6;
  #pragma unroll
  for (int p = 0; p < 16; ++p) {
    int kr = kq * 16 + p;
    tle[jc][kr] = src[(size_t)(k0 + kr) * ld + j0 + jc];
  }
  __syncthreads();
  #pragma unroll
  for (int p = 0; p < 16; ++p) {
    int jr = kq * 16 + p;
    out[(size_t)(j0 + jr) * K + k0 + jc] = f2bf(tle[jr][jc]);
  }
}

// ---------------- xW GEMM: A[M][512] @ Bt[N][512]^T + bias -> xw[M][3072] bf16 ----------------
// 128x128 tile, BK=64, 4 waves (2x2), 4x4 16x16x32 frags per wave, global_load_lds(16)
__global__ __launch_bounds__(256) void k_gemm(const u16* __restrict__ A,
                                              const u16* __restrict__ Bt,
                                              const float* __restrict__ bias,
                                              u16* __restrict__ xw) {
  __shared__ u16 lds[16384];  // lA [128][64] (chunks 0..1023) | lB [128][64] (1024..2047)
  const int Kd = 512;
  int n0 = blockIdx.x * 128, m0 = blockIdx.y * 128;
  int tid = threadIdx.x, lane = tid & 63, wave = tid >> 6;
  int wm = (wave >> 1) * 64, wn = (wave & 1) * 64;
  int l15 = lane & 15, lk8 = (lane >> 4) * 8;
  f32x4 acc[4][4];
  #pragma unroll
  for (int i = 0; i < 4; ++i)
    #pragma unroll
    for (int j = 0; j < 4; ++j) {
      acc[i][j][0] = 0.f; acc[i][j][1] = 0.f; acc[i][j][2] = 0.f; acc[i][j][3] = 0.f;
    }
  for (int k0 = 0; k0 < Kd; k0 += 64) {
    #pragma unroll
    for (int p = 0; p < 8; ++p) {
      int c = p * 256 + tid;
      int ldsbase = (c - lane) * 16;
      int row = (c & 1023) >> 3, colb = (c & 7) * 16;
      const char* g;
      if (c < 1024) g = (const char*)A  + ((size_t)(m0 + row) * Kd + k0) * 2 + colb;
      else          g = (const char*)Bt + ((size_t)(n0 + row) * Kd + k0) * 2 + colb;
      g2l16(g, (char*)lds + ldsbase);
    }
    __syncthreads();
    #pragma unroll
    for (int kk = 0; kk < 2; ++kk) {
      bf16x8 af[4], bfr[4];
      #pragma unroll
      for (int mf = 0; mf < 4; ++mf)
        af[mf] = *(const bf16x8*)&lds[(wm + mf * 16 + l15) * 64 + kk * 32 + lk8];
      #pragma unroll
      for (int nf = 0; nf < 4; ++nf)
        bfr[nf] = *(const bf16x8*)&lds[8192 + (wn + nf * 16 + l15) * 64 + kk * 32 + lk8];
      #pragma unroll
      for (int mf = 0; mf < 4; ++mf)
        #pragma unroll
        for (int nf = 0; nf < 4; ++nf)
          acc[mf][nf] = __builtin_amdgcn_mfma_f32_16x16x32_bf16(af[mf], bfr[nf], acc[mf][nf], 0, 0, 0);
    }
    __syncthreads();
  }
  int rbase = (lane >> 4) * 4;
  #pragma unroll
  for (int mf = 0; mf < 4; ++mf)
    #pragma unroll
    for (int nf = 0; nf < 4; ++nf) {
      int n = n0 + wn + nf * 16 + l15;
      float bv = bias[n];
      size_t mrow = (size_t)(m0 + wm + mf * 16 + rbase);
      #pragma unroll
      for (int r = 0; r < 4; ++r)
        xw[(mrow + r) * 3072 + n] = f2bf(acc[mf][nf][r] + bv);
    }
}

// ---------------- one recurrence step ----------------
// grid (64, 2): jb = 16 c-columns, rb = 64 batch rows. 320 threads = 5 waves,
// wave w computes gate-group w (U_i,U_f,U_g,P_i,P_f) for its 64x16 tile.
__global__ __launch_bounds__(320) void k_step(
    const float* __restrict__ cprev, const u16* __restrict__ cprevb,
    float* __restrict__ cnext, u16* __restrict__ cnextb,
    const u16* __restrict__ wcat, const u16* __restrict__ xw,
    const int* __restrict__ lens,
    float* __restrict__ sprev, float* __restrict__ snew, int t) {
  __shared__ u16 lds[9216];        // lA [64][64] (chunks 0..511) | lB [5][16][64] (512..1151)
  __shared__ float sg[5][64][16];  // gate partials
  int jb = blockIdx.x, rb = blockIdx.y;
  int tid = threadIdx.x, lane = tid & 63, wave = tid >> 6;
  int l15 = lane & 15, lk8 = (lane >> 4) * 8;
  f32x4 acc[4];
  #pragma unroll
  for (int i = 0; i < 4; ++i) { acc[i][0] = 0.f; acc[i][1] = 0.f; acc[i][2] = 0.f; acc[i][3] = 0.f; }

  for (int k0 = 0; k0 < 1024; k0 += 64) {
    #pragma unroll
    for (int p = 0; p < 4; ++p) {
      int c = p * 320 + tid;
      if (c < 1152) {  // wave-uniform cut (1152-960=192 = 3 full waves)
        int ldsbase = (c - lane) * 16;
        const char* g;
        if (c < 512) {  // A: c rows (bf16)
          int row = c >> 3, colb = (c & 7) * 16;
          g = (const char*)cprevb + ((size_t)(rb * 64 + row) * 1024 + k0) * 2 + colb;
        } else {        // B: wcat rows for the 5 gate groups
          int cb2 = c - 512;
          int reg = cb2 >> 7, rown = (cb2 >> 3) & 15, colb = (cb2 & 7) * 16;
          g = (const char*)wcat + ((size_t)(reg * 1024 + jb * 16 + rown) * 1024 + k0) * 2 + colb;
        }
        g2l16(g, (char*)lds + ldsbase);
      }
    }
    __syncthreads();
    #pragma unroll
    for (int kk = 0; kk < 2; ++kk) {
      bf16x8 bfr = *(const bf16x8*)&lds[4096 + (wave * 16 + l15) * 64 + kk * 32 + lk8];
      #pragma unroll
      for (int mf = 0; mf < 4; ++mf) {
        bf16x8 afr = *(const bf16x8*)&lds[(mf * 16 + l15) * 64 + kk * 32 + lk8];
        acc[mf] = __builtin_amdgcn_mfma_f32_16x16x32_bf16(afr, bfr, acc[mf], 0, 0, 0);
      }
    }
    __syncthreads();
  }
  int rbase = (lane >> 4) * 4;
  #pragma unroll
  for (int mf = 0; mf < 4; ++mf)
    #pragma unroll
    for (int r = 0; r < 4; ++r)
      sg[wave][mf * 16 + rbase + r][l15] = acc[mf][r];
  __syncthreads();

  for (int idx = tid; idx < 1024; idx += 320) {
    int rr = idx >> 4, cc = idx & 15;
    int b = rb * 64 + rr, j = jb * 16 + cc;
    const u16* xr = xw + (size_t)(b * 1024 + t) * 3072;
    float gi = sg[0][rr][cc] + bf2f(xr[j]);
    float gf = sg[1][rr][cc] + bf2f(xr[1024 + j]);
    float gg = sg[2][rr][cc] + bf2f(xr[2048 + j]);
    float pi = sg[3][rr][cc];
    float pf = sg[4][rr][cc];
    float it = sigm_(gi + tanh_(pi));
    float ft = sigm_(gf + tanh_(pf));
    float gt = tanh_(gg);
    float co = cprev[b * 1024 + j];
    float cn = ft * co + it * gt;
    cnext[b * 1024 + j] = cn;
    cnextb[b * 1024 + j] = f2bf(cn);
    if (t == lens[b] - 1) {
      sprev[b * 1024 + j] = co;
      snew[b * 1024 + j] = cn;
    }
  }
}

// ---------------- output pass: o-gate + h at t = lens[b]-1 ----------------
__global__ __launch_bounds__(256) void k_final(
    const int* __restrict__ lens, const float* __restrict__ x,
    const float* __restrict__ W, const float* __restrict__ U,
    const float* __restrict__ Po, const float* __restrict__ bias,
    const float* __restrict__ sp, const float* __restrict__ sn,
    float* __restrict__ out) {
  __shared__ float scp[1024], scn[1024], sx[512];
  int b = blockIdx.x, tid = threadIdx.x;
  int t = lens[b] - 1;
  for (int k = tid; k < 1024; k += 256) {
    scp[k] = sp[b * 1024 + k];
    scn[k] = sn[b * 1024 + k];
  }
  for (int k = tid; k < 512; k += 256)
    sx[k] = x[(size_t)(b * 1024 + t) * 512 + k];
  __syncthreads();
  for (int j = tid; j < 1024; j += 256) {
    float au = 0.f, ap = 0.f, ax = 0.f;
    for (int k = 0; k < 1024; ++k) {
      au = fmaf(scp[k], U[(size_t)k * 4096 + 3072 + j], au);
      ap = fmaf(scn[k], Po[(size_t)k * 1024 + j], ap);
    }
    for (int k = 0; k < 512; ++k)
      ax = fmaf(sx[k], W[(size_t)k * 4096 + 3072 + j], ax);
    float go = ax + bias[3072 + j] + au;
    float o = sigm_(go + tanh_(ap));
    out[b * 1024 + j] = o * tanh_(scn[j]);
  }
}

extern "C" void kernel_launch(void* const* d_in, const int* in_sizes, int n_in,
                              void* d_out, int out_size, void* d_ws, size_t ws_size,
                              hipStream_t stream) {
  const float* x    = (const float*)d_in[0];
  const int*   lens = (const int*)d_in[1];
  const float* W    = (const float*)d_in[2];
  const float* U    = (const float*)d_in[3];
  const float* P    = (const float*)d_in[4];
  const float* Po   = (const float*)d_in[5];
  const float* bias = (const float*)d_in[6];
  float* out = (float*)d_out;
  char* ws = (char*)d_ws;

  u16*   xw   = (u16*)(ws);
  u16*   xbf  = (u16*)(ws + 805306368LL);
  u16*   wt   = (u16*)(ws + 939524096LL);
  u16*   wcat = (u16*)(ws + 943718400LL);
  float* cf   = (float*)(ws + 954204160LL);
  u16*   cb   = (u16*)(ws + 955252736LL);
  float* sp   = (float*)(ws + 955777024LL);
  float* sn   = (float*)(ws + 956301312LL);

  // convert x -> bf16
  k_cvt<<<65536, 256, 0, stream>>>(x, xbf, 67108864);
  // W^T (ifg columns only) -> wt [3072][512]
  k_tr<<<dim3(48, 8), 256, 0, stream>>>(W, 4096, wt, 512);
  // pack Wcat^T [5120][1024]: rows 0..3071 = U cols 0..3071; rows 3072..5119 = P cols
  k_tr<<<dim3(48, 16), 256, 0, stream>>>(U, 4096, wcat, 1024);
  k_tr<<<dim3(32, 16), 256, 0, stream>>>(P, 2048, wcat + (size_t)3072 * 1024, 1024);
  // xW = x @ W[:, :3072] + bias  (bf16, row m = b*1024+t)
  k_gemm<<<dim3(24, 1024), 256, 0, stream>>>(xbf, wt, bias, xw);
  // zero c state (f32 ping-pong + bf16 shadow, contiguous)
  hipMemsetAsync(cf, 0, 2 * 524288 + 2 * 262144, stream);
  // sequential recurrence
  for (int t = 0; t < 1024; ++t) {
    const float* cp = cf + (size_t)(t & 1) * 131072;
    float* cn = cf + (size_t)((t + 1) & 1) * 131072;
    const u16* cpb = cb + (size_t)(t & 1) * 131072;
    u16* cnb = cb + (size_t)((t + 1) & 1) * 131072;
    k_step<<<dim3(64, 2), 320, 0, stream>>>(cp, cpb, cn, cnb, wcat, xw, lens, sp, sn, t);
  }
  // output gate + h at each row's output step
  k_final<<<128, 256, 0, stream>>>(lens, x, W, U, Po, bias, sp, sn, out);
}